// Round 6
// baseline (442.800 us; speedup 1.0000x reference)
//
#include <hip/hip_runtime.h>
#include <stdint.h>

#define DD 1024

typedef float f32x4 __attribute__((ext_vector_type(4)));

// DPP lane permute: CTRL = quad_perm / mirror encodings.
// xor1=0xB1, xor2=0x4E, xor3=0x1B, half_mirror(xor7)=0x141, row_mirror(xor15)=0x140
template <int CTRL>
__device__ __forceinline__ float xdpp(float v) {
  return __int_as_float(__builtin_amdgcn_update_dpp(
      0, __float_as_int(v), CTRL, 0xF, 0xF, true));
}

// In-register FWHT over 16 values (h = 1,2,4,8 within the register index).
__device__ __forceinline__ void fwht16(float (&v)[16]) {
  #pragma unroll
  for (int h = 1; h < 16; h <<= 1) {
    #pragma unroll
    for (int i = 0; i < 16; ++i) {
      if (!(i & h)) {
        float a = v[i], b = v[i | h];
        v[i]     = a + b;
        v[i | h] = a - b;
      }
    }
  }
}

// Full 1024-point WHT on e = 16*lane + j. Cross-lane stages are lane-XOR
// butterflies: h=16..512 <-> lane masks 1,2,4,8,16,32.
// sgN = (lane & N) ? -1 : +1 ; butterfly: v = o + sgN*v  (o = partner value)
__device__ __forceinline__ void wht1024(float (&v)[16],
    float sg1, float sg2, float sg4, float sg8, float sg16, float sg32) {
  fwht16(v);
  #pragma unroll
  for (int j = 0; j < 16; ++j) {             // h=16 : lane^1 (quad_perm)
    float o = xdpp<0xB1>(v[j]);
    v[j] = fmaf(sg1, v[j], o);
  }
  #pragma unroll
  for (int j = 0; j < 16; ++j) {             // h=32 : lane^2 (quad_perm)
    float o = xdpp<0x4E>(v[j]);
    v[j] = fmaf(sg2, v[j], o);
  }
  #pragma unroll
  for (int j = 0; j < 16; ++j) {             // h=64 : lane^4 = xor3 o xor7 (DPP)
    float o = xdpp<0x141>(xdpp<0x1B>(v[j]));
    v[j] = fmaf(sg4, v[j], o);
  }
  #pragma unroll
  for (int j = 0; j < 16; ++j) {             // h=128: lane^8 = xor7 o xor15 (DPP)
    float o = xdpp<0x140>(xdpp<0x141>(v[j]));
    v[j] = fmaf(sg8, v[j], o);
  }
  #pragma unroll
  for (int j = 0; j < 16; ++j) {             // h=256: lane^16 (ds_swizzle xor16)
    float o = __int_as_float(
        __builtin_amdgcn_ds_swizzle(__float_as_int(v[j]), 0x401F));
    v[j] = fmaf(sg16, v[j], o);
  }
  #pragma unroll
  for (int j = 0; j < 16; ++j) {             // h=512: lane^32
    float o = __shfl_xor(v[j], 32, 64);
    v[j] = fmaf(sg32, v[j], o);
  }
}

__device__ __forceinline__ void load_row(const float* __restrict__ x, long r,
                                         int lane, float (&v)[16]) {
  const f32x4* p = (const f32x4*)(x + r * (long)DD + 16 * lane);
  #pragma unroll
  for (int c = 0; c < 4; ++c) {
    f32x4 a = p[c];
    v[4 * c + 0] = a.x; v[4 * c + 1] = a.y;
    v[4 * c + 2] = a.z; v[4 * c + 3] = a.w;
  }
}

// Apply sign0 (packed bits) -> WHT -> sign1 -> WHT -> *1/1024 -> store.
__device__ __forceinline__ void proc_store(float (&v)[16],
    float* __restrict__ out, long r, int lane, uint32_t s0p, uint32_t s1p,
    float sg1, float sg2, float sg4, float sg8, float sg16, float sg32) {
  #pragma unroll
  for (int j = 0; j < 16; ++j)
    v[j] = __uint_as_float(__float_as_uint(v[j]) ^
                           ((s0p << (31 - j)) & 0x80000000u));
  wht1024(v, sg1, sg2, sg4, sg8, sg16, sg32);
  #pragma unroll
  for (int j = 0; j < 16; ++j)
    v[j] = __uint_as_float(__float_as_uint(v[j]) ^
                           ((s1p << (31 - j)) & 0x80000000u));
  wht1024(v, sg1, sg2, sg4, sg8, sg16, sg32);

  f32x4* op = (f32x4*)(out + r * (long)DD + 16 * lane);
  const float S = 1.0f / 1024.0f;  // both 1/32 scales commute through H
  #pragma unroll
  for (int c = 0; c < 4; ++c) {
    f32x4 o4;
    o4.x = v[4 * c + 0] * S; o4.y = v[4 * c + 1] * S;
    o4.z = v[4 * c + 2] * S; o4.w = v[4 * c + 3] * S;
    op[c] = o4;
  }
}

// Persistent waves, zero LDS, register double-buffer (unroll-2, static regs).
__global__ __launch_bounds__(256, 8) void srht_kernel(
    const float* __restrict__ x, const float* __restrict__ signs,
    float* __restrict__ out, int iters, int wstride, int rows)
{
  const int lane = threadIdx.x & 63;
  const int gw   = blockIdx.x * 4 + (threadIdx.x >> 6);

  // ---- pack both sign rows into one bit-word per lane (bit j = signbit) ----
  uint32_t s0p = 0, s1p = 0;
  {
    const f32x4* sp0 = (const f32x4*)(signs + 16 * lane);
    const f32x4* sp1 = (const f32x4*)(signs + DD + 16 * lane);
    #pragma unroll
    for (int c = 0; c < 4; ++c) {
      f32x4 a = sp0[c], b = sp1[c];
      s0p |= (__float_as_uint(a.x) >> 31) << (4 * c + 0);
      s0p |= (__float_as_uint(a.y) >> 31) << (4 * c + 1);
      s0p |= (__float_as_uint(a.z) >> 31) << (4 * c + 2);
      s0p |= (__float_as_uint(a.w) >> 31) << (4 * c + 3);
      s1p |= (__float_as_uint(b.x) >> 31) << (4 * c + 0);
      s1p |= (__float_as_uint(b.y) >> 31) << (4 * c + 1);
      s1p |= (__float_as_uint(b.z) >> 31) << (4 * c + 2);
      s1p |= (__float_as_uint(b.w) >> 31) << (4 * c + 3);
    }
  }
  const float sg1  = (lane & 1)  ? -1.f : 1.f;
  const float sg2  = (lane & 2)  ? -1.f : 1.f;
  const float sg4  = (lane & 4)  ? -1.f : 1.f;
  const float sg8  = (lane & 8)  ? -1.f : 1.f;
  const float sg16 = (lane & 16) ? -1.f : 1.f;
  const float sg32 = (lane & 32) ? -1.f : 1.f;

  float vA[16], vB[16];
  long rA = gw;
  long rB = gw + (long)wstride;
  if (rB >= rows) rB = gw;       // clamped prefetch: harmless re-read
  load_row(x, rA, lane, vA);
  load_row(x, rB, lane, vB);

  for (int it = 0; it < iters; it += 2) {
    proc_store(vA, out, rA, lane, s0p, s1p, sg1, sg2, sg4, sg8, sg16, sg32);
    {
      long rn = rA + 2L * wstride;
      if (rn >= rows) rn = gw;
      load_row(x, rn, lane, vA);   // in flight during vB's compute
      rA = rn;
    }
    if (it + 1 < iters) {
      proc_store(vB, out, rB, lane, s0p, s1p, sg1, sg2, sg4, sg8, sg16, sg32);
      long rn = rB + 2L * wstride;
      if (rn >= rows) rn = gw;
      load_row(x, rn, lane, vB);   // in flight during next vA's compute
      rB = rn;
    }
  }

  // generic tail (unused at rows=65536 with 8192 waves)
  long rt = (long)iters * wstride + gw;
  if (rt < rows) {
    load_row(x, rt, lane, vA);
    proc_store(vA, out, rt, lane, s0p, s1p, sg1, sg2, sg4, sg8, sg16, sg32);
  }
}

extern "C" void kernel_launch(void* const* d_in, const int* in_sizes, int n_in,
                              void* d_out, int out_size, void* d_ws, size_t ws_size,
                              hipStream_t stream) {
  const float* x     = (const float*)d_in[0];
  const float* signs = (const float*)d_in[1];
  float* out         = (float*)d_out;

  const int rows   = in_sizes[0] / DD;  // 65536
  const int blocks = 2048;              // 8 blocks/CU -> 32 waves/CU, LDS = 0
  const int waves  = blocks * 4;        // 8192
  const int iters  = rows / waves;      // 8 (remainder handled by tail)

  hipLaunchKernelGGL(srht_kernel, dim3(blocks), dim3(256), 0, stream,
                     x, signs, out, iters, waves, rows);
}

// Round 7
// 147.405 us; speedup vs baseline: 3.0040x; 3.0040x over previous
//
#include <hip/hip_runtime.h>
#include <stdint.h>

#define DD 1024

typedef float f32x4 __attribute__((ext_vector_type(4)));

// DPP lane permute: CTRL = quad_perm / mirror encodings.
// xor1=0xB1, xor2=0x4E, xor3=0x1B, half_mirror(xor7)=0x141, row_mirror(xor15)=0x140
template <int CTRL>
__device__ __forceinline__ float xdpp(float v) {
  return __int_as_float(__builtin_amdgcn_update_dpp(
      0, __float_as_int(v), CTRL, 0xF, 0xF, true));
}

// In-register FWHT over 16 values (h = 1,2,4,8 within the register index).
__device__ __forceinline__ void fwht16(float (&v)[16]) {
  #pragma unroll
  for (int h = 1; h < 16; h <<= 1) {
    #pragma unroll
    for (int i = 0; i < 16; ++i) {
      if (!(i & h)) {
        float a = v[i], b = v[i | h];
        v[i]     = a + b;
        v[i | h] = a - b;
      }
    }
  }
}

// Full 1024-point WHT on e = 16*lane + j. Cross-lane stages are lane-XOR
// butterflies: h=16..512 <-> lane masks 1,2,4,8,16,32.
// sgN = (lane & N) ? -1 : +1 ; butterfly: v = o + sgN*v  (o = partner value)
__device__ __forceinline__ void wht1024(float (&v)[16],
    float sg1, float sg2, float sg4, float sg8, float sg16, float sg32) {
  fwht16(v);
  #pragma unroll
  for (int j = 0; j < 16; ++j) {             // h=16 : lane^1 (quad_perm)
    float o = xdpp<0xB1>(v[j]);
    v[j] = fmaf(sg1, v[j], o);
  }
  #pragma unroll
  for (int j = 0; j < 16; ++j) {             // h=32 : lane^2 (quad_perm)
    float o = xdpp<0x4E>(v[j]);
    v[j] = fmaf(sg2, v[j], o);
  }
  #pragma unroll
  for (int j = 0; j < 16; ++j) {             // h=64 : lane^4 = xor3 o xor7 (DPP)
    float o = xdpp<0x141>(xdpp<0x1B>(v[j]));
    v[j] = fmaf(sg4, v[j], o);
  }
  #pragma unroll
  for (int j = 0; j < 16; ++j) {             // h=128: lane^8 = xor7 o xor15 (DPP)
    float o = xdpp<0x140>(xdpp<0x141>(v[j]));
    v[j] = fmaf(sg8, v[j], o);
  }
  #pragma unroll
  for (int j = 0; j < 16; ++j) {             // h=256: lane^16 (ds_swizzle xor16)
    float o = __int_as_float(
        __builtin_amdgcn_ds_swizzle(__float_as_int(v[j]), 0x401F));
    v[j] = fmaf(sg16, v[j], o);
  }
  #pragma unroll
  for (int j = 0; j < 16; ++j) {             // h=512: lane^32
    float o = __shfl_xor(v[j], 32, 64);
    v[j] = fmaf(sg32, v[j], o);
  }
}

// Non-persistent: one row per wave, zero LDS, ~45 VGPR -> full occupancy.
// TLP (32 waves/CU) hides HBM latency; no register double-buffer, no spill.
__global__ __launch_bounds__(256) void srht_kernel(
    const float* __restrict__ x, const float* __restrict__ signs,
    float* __restrict__ out)
{
  const int lane = threadIdx.x & 63;
  const long row = (long)blockIdx.x * 4 + (threadIdx.x >> 6);

  // ---- issue the row load first (16B/lane x 4, coalesced 1KB/instr) ----
  float v[16];
  {
    const f32x4* p = (const f32x4*)(x + row * DD + 16 * lane);
    #pragma unroll
    for (int c = 0; c < 4; ++c) {
      f32x4 a = p[c];
      v[4 * c + 0] = a.x; v[4 * c + 1] = a.y;
      v[4 * c + 2] = a.z; v[4 * c + 3] = a.w;
    }
  }

  // ---- pack both sign rows into one bit-word per lane (bit j = signbit) ----
  uint32_t s0p = 0, s1p = 0;
  {
    const f32x4* sp0 = (const f32x4*)(signs + 16 * lane);
    const f32x4* sp1 = (const f32x4*)(signs + DD + 16 * lane);
    #pragma unroll
    for (int c = 0; c < 4; ++c) {
      f32x4 a = sp0[c], b = sp1[c];
      s0p |= (__float_as_uint(a.x) >> 31) << (4 * c + 0);
      s0p |= (__float_as_uint(a.y) >> 31) << (4 * c + 1);
      s0p |= (__float_as_uint(a.z) >> 31) << (4 * c + 2);
      s0p |= (__float_as_uint(a.w) >> 31) << (4 * c + 3);
      s1p |= (__float_as_uint(b.x) >> 31) << (4 * c + 0);
      s1p |= (__float_as_uint(b.y) >> 31) << (4 * c + 1);
      s1p |= (__float_as_uint(b.z) >> 31) << (4 * c + 2);
      s1p |= (__float_as_uint(b.w) >> 31) << (4 * c + 3);
    }
  }
  const float sg1  = (lane & 1)  ? -1.f : 1.f;
  const float sg2  = (lane & 2)  ? -1.f : 1.f;
  const float sg4  = (lane & 4)  ? -1.f : 1.f;
  const float sg8  = (lane & 8)  ? -1.f : 1.f;
  const float sg16 = (lane & 16) ? -1.f : 1.f;
  const float sg32 = (lane & 32) ? -1.f : 1.f;

  // ---- sign0 -> WHT -> sign1 -> WHT -> *1/1024 (both 1/32 commute) ----
  #pragma unroll
  for (int j = 0; j < 16; ++j)
    v[j] = __uint_as_float(__float_as_uint(v[j]) ^
                           ((s0p << (31 - j)) & 0x80000000u));
  wht1024(v, sg1, sg2, sg4, sg8, sg16, sg32);
  #pragma unroll
  for (int j = 0; j < 16; ++j)
    v[j] = __uint_as_float(__float_as_uint(v[j]) ^
                           ((s1p << (31 - j)) & 0x80000000u));
  wht1024(v, sg1, sg2, sg4, sg8, sg16, sg32);

  {
    f32x4* op = (f32x4*)(out + row * DD + 16 * lane);
    const float S = 1.0f / 1024.0f;
    #pragma unroll
    for (int c = 0; c < 4; ++c) {
      f32x4 o4;
      o4.x = v[4 * c + 0] * S; o4.y = v[4 * c + 1] * S;
      o4.z = v[4 * c + 2] * S; o4.w = v[4 * c + 3] * S;
      op[c] = o4;
    }
  }
}

extern "C" void kernel_launch(void* const* d_in, const int* in_sizes, int n_in,
                              void* d_out, int out_size, void* d_ws, size_t ws_size,
                              hipStream_t stream) {
  const float* x     = (const float*)d_in[0];
  const float* signs = (const float*)d_in[1];
  float* out         = (float*)d_out;

  const int rows   = in_sizes[0] / DD;  // 65536
  const int blocks = rows / 4;          // one row per wave, 4 waves/block

  hipLaunchKernelGGL(srht_kernel, dim3(blocks), dim3(256), 0, stream,
                     x, signs, out);
}

// Round 8
// 132.092 us; speedup vs baseline: 3.3522x; 1.1159x over previous
//
#include <hip/hip_runtime.h>
#include <stdint.h>

#define DD 1024

typedef float f32x4 __attribute__((ext_vector_type(4)));

// DPP quad_perm lane permute: xor1 = 0xB1, xor2 = 0x4E (verified R7).
template <int CTRL>
__device__ __forceinline__ float xdpp(float v) {
  return __int_as_float(__builtin_amdgcn_update_dpp(
      0, __float_as_int(v), CTRL, 0xF, 0xF, true));
}

// In-register FWHT over 16 values (strides 1,2,4,8 in the register index).
__device__ __forceinline__ void fwht16(float (&v)[16]) {
  #pragma unroll
  for (int h = 1; h < 16; h <<= 1) {
    #pragma unroll
    for (int i = 0; i < 16; ++i) {
      if (!(i & h)) {
        float a = v[i], b = v[i | h];
        v[i]     = a + b;
        v[i | h] = a - b;
      }
    }
  }
}

__device__ __forceinline__ void load_row(const float* __restrict__ x, long r,
                                         int lane, float (&v)[16]) {
  const f32x4* p = (const f32x4*)(x + r * (long)DD + 16 * lane);
  #pragma unroll
  for (int c = 0; c < 4; ++c) {
    f32x4 a = p[c];
    v[4 * c + 0] = a.x; v[4 * c + 1] = a.y;
    v[4 * c + 2] = a.z; v[4 * c + 3] = a.w;
  }
}

__device__ __forceinline__ void store_row(float* __restrict__ out, long r,
                                          int lane, const float (&res)[16]) {
  f32x4* op = (f32x4*)(out + r * (long)DD + 16 * lane);
  #pragma unroll
  for (int c = 0; c < 4; ++c) {
    f32x4 o4 = {res[4 * c + 0], res[4 * c + 1], res[4 * c + 2], res[4 * c + 3]};
    op[c] = o4;
  }
}

// One full SRHT row (2x WHT + signs + scale), R4-verified LDS XOR-swizzle
// transposes, R7-verified DPP butterflies for lane masks 1,2.
// v is consumed in place; result lands in res (so the caller can overwrite v
// with a prefetch while res's store is outstanding).
__device__ __forceinline__ void process_row(
    float (&v)[16], float (&res)[16], float* __restrict__ buf,
    const float (&s1v)[16], uint32_t s0p, float sg1, float sg2,
    int abase, int qL, int base_e, int base_o)
{
  // sign0 via packed sign bits
  #pragma unroll
  for (int j = 0; j < 16; ++j)
    v[j] = __uint_as_float(__float_as_uint(v[j]) ^
                           ((s0p << (31 - j)) & 0x80000000u));

  // pass 1, A-stages: h=1..8 in-register, h=16/32 via DPP
  fwht16(v);
  #pragma unroll
  for (int j = 0; j < 16; ++j) { float o = xdpp<0xB1>(v[j]); v[j] = fmaf(sg1, v[j], o); }
  #pragma unroll
  for (int j = 0; j < 16; ++j) { float o = xdpp<0x4E>(v[j]); v[j] = fmaf(sg2, v[j], o); }

  // transpose A -> B (swizzled: b128 writes, b32 reads w/ immediate offsets)
  #pragma unroll
  for (int c = 0; c < 4; ++c) {
    f32x4 w4 = {v[4 * c], v[4 * c + 1], v[4 * c + 2], v[4 * c + 3]};
    *(f32x4*)(buf + abase + 4 * (c ^ qL)) = w4;
  }
  #pragma unroll
  for (int k = 0; k < 16; ++k)
    v[k] = buf[((k & 1) ? base_o : base_e) + 64 * k];

  fwht16(v);                                   // pass 1 h=64..512

  #pragma unroll
  for (int k = 0; k < 16; ++k) v[k] *= s1v[k]; // sign1 * (1/1024)

  fwht16(v);                                   // pass 2 h=64..512

  // transpose B -> A
  #pragma unroll
  for (int k = 0; k < 16; ++k)
    buf[((k & 1) ? base_o : base_e) + 64 * k] = v[k];
  #pragma unroll
  for (int c = 0; c < 4; ++c) {
    f32x4 r4 = *(const f32x4*)(buf + abase + 4 * (c ^ qL));
    res[4 * c + 0] = r4.x; res[4 * c + 1] = r4.y;
    res[4 * c + 2] = r4.z; res[4 * c + 3] = r4.w;
  }

  // pass 2, A-stages
  #pragma unroll
  for (int j = 0; j < 16; ++j) { float o = xdpp<0xB1>(res[j]); res[j] = fmaf(sg1, res[j], o); }
  #pragma unroll
  for (int j = 0; j < 16; ++j) { float o = xdpp<0x4E>(res[j]); res[j] = fmaf(sg2, res[j], o); }
  fwht16(res);
}

// Persistent-lite: 8 rows/wave, ping-pong register prefetch (vA/vB static
// names), wave-private LDS slice, no barriers, no launch_bounds min-waves.
__global__ __launch_bounds__(256) void srht_kernel(
    const float* __restrict__ x, const float* __restrict__ signs,
    float* __restrict__ out, int iters, int NW, int rows)
{
  __shared__ float lds[4][DD];  // 16 KB/block, wave-private slices
  const int lane = threadIdx.x & 63;
  const int wv   = threadIdx.x >> 6;
  const int gw   = blockIdx.x * 4 + wv;
  if (gw >= rows) return;
  float* buf = lds[wv];

  // A-layout swizzled float4 addressing (verified R4)
  const int qL    = (lane >> 1) & 3;
  const int abase = 16 * lane;
  // B-layout swizzled addressing (verified R4)
  const int lu = lane >> 4;
  const int hb = (lane >> 5) & 1;
  const int m  = (lane >> 2) & 3;
  const int t  = lane & 3;
  const int base_e = 16 * lu + 4 * (m ^ hb) + t;
  const int base_o = 16 * lu + 4 * (m ^ ((hb + 2) & 3)) + t;

  const float sg1 = (lane & 1) ? -1.f : 1.f;
  const float sg2 = (lane & 2) ? -1.f : 1.f;

  // sign0 packed to bits; sign1 pre-scaled by 1/1024 (both 1/32 commute)
  uint32_t s0p = 0;
  {
    const f32x4* sp0 = (const f32x4*)(signs + 16 * lane);
    #pragma unroll
    for (int c = 0; c < 4; ++c) {
      f32x4 a = sp0[c];
      s0p |= (__float_as_uint(a.x) >> 31) << (4 * c + 0);
      s0p |= (__float_as_uint(a.y) >> 31) << (4 * c + 1);
      s0p |= (__float_as_uint(a.z) >> 31) << (4 * c + 2);
      s0p |= (__float_as_uint(a.w) >> 31) << (4 * c + 3);
    }
  }
  float s1v[16];
  #pragma unroll
  for (int k = 0; k < 16; ++k)
    s1v[k] = signs[DD + lane + 64 * k] * (1.0f / 1024.0f);

  float vA[16], vB[16], res[16];
  long rA = gw;
  long rB = gw + (long)NW;
  load_row(x, rA, lane, vA);
  if (iters > 1) load_row(x, rB, lane, vB);

  for (int it = 0; it + 1 < iters; it += 2) {
    // phase A: compute row rA; prefetch row rA+2NW during B's compute
    process_row(vA, res, buf, s1v, s0p, sg1, sg2, abase, qL, base_e, base_o);
    store_row(out, rA, lane, res);
    long rnA = rA + 2L * NW;
    if (it + 2 < iters && rnA < rows) load_row(x, rnA, lane, vA);

    // phase B
    process_row(vB, res, buf, s1v, s0p, sg1, sg2, abase, qL, base_e, base_o);
    store_row(out, rB, lane, res);
    long rnB = rB + 2L * NW;
    if (it + 3 < iters && rnB < rows) load_row(x, rnB, lane, vB);

    rA = rnA; rB = rnB;
  }
  if (iters & 1) {  // tail (unused at rows=65536)
    process_row(vA, res, buf, s1v, s0p, sg1, sg2, abase, qL, base_e, base_o);
    store_row(out, rA, lane, res);
  }
}

extern "C" void kernel_launch(void* const* d_in, const int* in_sizes, int n_in,
                              void* d_out, int out_size, void* d_ws, size_t ws_size,
                              hipStream_t stream) {
  const float* x     = (const float*)d_in[0];
  const float* signs = (const float*)d_in[1];
  float* out         = (float*)d_out;

  const int rows = in_sizes[0] / DD;  // 65536
  int blocks = 2048;                  // 8 blocks/CU nominal
  if (rows < blocks * 4) blocks = (rows + 3) / 4;
  const int NW    = blocks * 4;       // 8192 waves
  const int iters = (rows + NW - 1) / NW;  // 8

  hipLaunchKernelGGL(srht_kernel, dim3(blocks), dim3(256), 0, stream,
                     x, signs, out, iters, NW, rows);
}

// Round 9
// 129.563 us; speedup vs baseline: 3.4176x; 1.0195x over previous
//
#include <hip/hip_runtime.h>
#include <stdint.h>

#define DD 1024

typedef float f32x4 __attribute__((ext_vector_type(4)));

// DPP quad_perm lane permute: xor1 = 0xB1, xor2 = 0x4E (verified R7/R8).
template <int CTRL>
__device__ __forceinline__ float xdpp(float v) {
  return __int_as_float(__builtin_amdgcn_update_dpp(
      0, __float_as_int(v), CTRL, 0xF, 0xF, true));
}

// In-register FWHT over 16 values (strides 1,2,4,8 in the register index).
__device__ __forceinline__ void fwht16(float (&v)[16]) {
  #pragma unroll
  for (int h = 1; h < 16; h <<= 1) {
    #pragma unroll
    for (int i = 0; i < 16; ++i) {
      if (!(i & h)) {
        float a = v[i], b = v[i | h];
        v[i]     = a + b;
        v[i | h] = a - b;
      }
    }
  }
}

// Two rows per wave, fully independent chains (disjoint LDS slices) so the
// compiler can interleave them — cross-row ILP inside the wave, not just TLP.
// Verified pieces: A/B XOR-swizzle transpose (R4), DPP butterflies (R7).
__global__ __launch_bounds__(256) void srht_kernel(
    const float* __restrict__ x, const float* __restrict__ signs,
    float* __restrict__ out)
{
  __shared__ float lds[8][DD];  // 32 KB/block; wave wv owns slices wv and wv+4
  const int lane = threadIdx.x & 63;
  const int wv   = threadIdx.x >> 6;
  const long base = (long)blockIdx.x * 8;
  const long r0 = base + wv;
  const long r1 = base + 4 + wv;
  float* buf0 = lds[wv];
  float* buf1 = lds[wv + 4];

  // A-layout swizzled float4 addressing (verified R4)
  const int qL    = (lane >> 1) & 3;
  const int abase = 16 * lane;
  // B-layout swizzled addressing (verified R4)
  const int lu = lane >> 4;
  const int hb = (lane >> 5) & 1;
  const int m  = (lane >> 2) & 3;
  const int t  = lane & 3;
  const int base_e = 16 * lu + 4 * (m ^ hb) + t;
  const int base_o = 16 * lu + 4 * (m ^ ((hb + 2) & 3)) + t;

  const float sg1 = (lane & 1) ? -1.f : 1.f;
  const float sg2 = (lane & 2) ? -1.f : 1.f;

  // ---- issue sign loads first, then both row loads (all in flight) ----
  f32x4 s0r[4];
  {
    const f32x4* sp0 = (const f32x4*)(signs + 16 * lane);
    #pragma unroll
    for (int c = 0; c < 4; ++c) s0r[c] = sp0[c];
  }
  float s1v[16];  // sign1 pre-scaled by 1/1024 (both 1/32 scales commute)
  #pragma unroll
  for (int k = 0; k < 16; ++k)
    s1v[k] = signs[DD + lane + 64 * k] * (1.0f / 1024.0f);

  float v0[16], v1[16];
  {
    const f32x4* p0 = (const f32x4*)(x + r0 * DD + 16 * lane);
    const f32x4* p1 = (const f32x4*)(x + r1 * DD + 16 * lane);
    #pragma unroll
    for (int c = 0; c < 4; ++c) {
      f32x4 a = p0[c], b = p1[c], s = s0r[c];
      v0[4 * c + 0] = a.x * s.x; v1[4 * c + 0] = b.x * s.x;
      v0[4 * c + 1] = a.y * s.y; v1[4 * c + 1] = b.y * s.y;
      v0[4 * c + 2] = a.z * s.z; v1[4 * c + 2] = b.z * s.z;
      v0[4 * c + 3] = a.w * s.w; v1[4 * c + 3] = b.w * s.w;
    }
  }

  // ---- pass 1, A-stages: h=1..8 in-register, h=16/32 via DPP ----
  fwht16(v0);
  fwht16(v1);
  #pragma unroll
  for (int j = 0; j < 16; ++j) {
    float o0 = xdpp<0xB1>(v0[j]); v0[j] = fmaf(sg1, v0[j], o0);
    float o1 = xdpp<0xB1>(v1[j]); v1[j] = fmaf(sg1, v1[j], o1);
  }
  #pragma unroll
  for (int j = 0; j < 16; ++j) {
    float o0 = xdpp<0x4E>(v0[j]); v0[j] = fmaf(sg2, v0[j], o0);
    float o1 = xdpp<0x4E>(v1[j]); v1[j] = fmaf(sg2, v1[j], o1);
  }

  // ---- transpose A -> B (disjoint buffers; chains stay independent) ----
  #pragma unroll
  for (int c = 0; c < 4; ++c) {
    f32x4 w0 = {v0[4 * c], v0[4 * c + 1], v0[4 * c + 2], v0[4 * c + 3]};
    f32x4 w1 = {v1[4 * c], v1[4 * c + 1], v1[4 * c + 2], v1[4 * c + 3]};
    *(f32x4*)(buf0 + abase + 4 * (c ^ qL)) = w0;
    *(f32x4*)(buf1 + abase + 4 * (c ^ qL)) = w1;
  }
  #pragma unroll
  for (int k = 0; k < 16; ++k) {
    const int off = ((k & 1) ? base_o : base_e) + 64 * k;
    v0[k] = buf0[off];
    v1[k] = buf1[off];
  }

  // ---- pass 1 h=64..512 ; sign1*scale ; pass 2 h=64..512 ----
  fwht16(v0);
  fwht16(v1);
  #pragma unroll
  for (int k = 0; k < 16; ++k) { v0[k] *= s1v[k]; v1[k] *= s1v[k]; }
  fwht16(v0);
  fwht16(v1);

  // ---- transpose B -> A ----
  #pragma unroll
  for (int k = 0; k < 16; ++k) {
    const int off = ((k & 1) ? base_o : base_e) + 64 * k;
    buf0[off] = v0[k];
    buf1[off] = v1[k];
  }
  #pragma unroll
  for (int c = 0; c < 4; ++c) {
    f32x4 a = *(const f32x4*)(buf0 + abase + 4 * (c ^ qL));
    f32x4 b = *(const f32x4*)(buf1 + abase + 4 * (c ^ qL));
    v0[4 * c + 0] = a.x; v1[4 * c + 0] = b.x;
    v0[4 * c + 1] = a.y; v1[4 * c + 1] = b.y;
    v0[4 * c + 2] = a.z; v1[4 * c + 2] = b.z;
    v0[4 * c + 3] = a.w; v1[4 * c + 3] = b.w;
  }

  // ---- pass 2, A-stages ----
  #pragma unroll
  for (int j = 0; j < 16; ++j) {
    float o0 = xdpp<0xB1>(v0[j]); v0[j] = fmaf(sg1, v0[j], o0);
    float o1 = xdpp<0xB1>(v1[j]); v1[j] = fmaf(sg1, v1[j], o1);
  }
  #pragma unroll
  for (int j = 0; j < 16; ++j) {
    float o0 = xdpp<0x4E>(v0[j]); v0[j] = fmaf(sg2, v0[j], o0);
    float o1 = xdpp<0x4E>(v1[j]); v1[j] = fmaf(sg2, v1[j], o1);
  }
  fwht16(v0);
  fwht16(v1);

  // ---- store both rows (coalesced float4) ----
  {
    f32x4* op0 = (f32x4*)(out + r0 * DD + 16 * lane);
    f32x4* op1 = (f32x4*)(out + r1 * DD + 16 * lane);
    #pragma unroll
    for (int c = 0; c < 4; ++c) {
      f32x4 o0 = {v0[4 * c], v0[4 * c + 1], v0[4 * c + 2], v0[4 * c + 3]};
      f32x4 o1 = {v1[4 * c], v1[4 * c + 1], v1[4 * c + 2], v1[4 * c + 3]};
      op0[c] = o0;
      op1[c] = o1;
    }
  }
}

extern "C" void kernel_launch(void* const* d_in, const int* in_sizes, int n_in,
                              void* d_out, int out_size, void* d_ws, size_t ws_size,
                              hipStream_t stream) {
  const float* x     = (const float*)d_in[0];
  const float* signs = (const float*)d_in[1];
  float* out         = (float*)d_out;

  const int rows   = in_sizes[0] / DD;  // 65536
  const int blocks = rows / 8;          // 2 rows per wave, 4 waves per block

  hipLaunchKernelGGL(srht_kernel, dim3(blocks), dim3(256), 0, stream,
                     x, signs, out);
}